// Round 2
// 471.765 us; speedup vs baseline: 1.0014x; 1.0014x over previous
//
#include <hip/hip_runtime.h>

// x: (8,1,1024,1024) f32, y: (8,12,1024,1024) f32, out: scalar f32
// loss = mean(|pred - x|), pred for output pixel (b,H,W):
//   c = (H%4)*4 + (W%4)
//   pred = y[b, CH[c], (H&~3) + RO[c], W]   (W-phase of cell c == W%4 always)
// Includes the reference's _PERM[15]=5 bug: c=15 -> (ch=4, ro=0).
//
// R2 (resubmit after container-infra failure): one thread per 4x4 output
// tile. All VMEM is coalesced dwordx4: 4 x-row float4 loads + 16 y-row
// float4 loads per thread. The y float4s carry the same 64B lines the
// scalar gather fetched anyway (stride-16B within touched rows), but now
// the loads are contiguous 1KiB/wave bursts with 20 independent loads in
// flight per thread. 2048 blocks x 256 thr.

#define NBLOCKS 2048

__global__ __launch_bounds__(256) void loss_partial_kernel(
        const float* __restrict__ x, const float* __restrict__ y,
        float* __restrict__ partial) {
    // cell c -> source channel / row offset (decoded from reference, incl. bug)
    constexpr unsigned CH[16] = {0,3,1,4, 6,9,7,10, 1,4,2,5, 8,10,9,4};
    constexpr unsigned RO[16] = {0,0,0,0, 1,1,1,1, 2,2,2,2, 3,3,3,0};

    unsigned t = blockIdx.x * 256u + threadIdx.x;   // one 4x4 tile per thread
    unsigned b = t >> 16;          // batch            (65536 tiles per batch)
    unsigned g = (t >> 8) & 255u;  // H-group (H = 4g + hmod)
    unsigned k = t & 255u;         // W-group (W = 4k + wp), consecutive lanes
                                   //   -> consecutive 16B: fully coalesced

    // ---- x tile: 4 coalesced float4 row loads ----
    unsigned xbase = (b << 20) + (g << 12) + (k << 2);   // float index
    float4 xr[4];
    xr[0] = *reinterpret_cast<const float4*>(x + xbase);
    xr[1] = *reinterpret_cast<const float4*>(x + xbase + 1024u);
    xr[2] = *reinterpret_cast<const float4*>(x + xbase + 2048u);
    xr[3] = *reinterpret_cast<const float4*>(x + xbase + 3072u);

    // ---- y: 16 coalesced float4 row loads, one per cell ----
    // float index = (b*12 + ch)<<20 | (4g + ro)<<10 | 4k
    unsigned ybase = (b * 12u << 20) + (g << 12) + (k << 2);

    float acc = 0.0f;
#pragma unroll
    for (int c = 0; c < 16; ++c) {
        unsigned off = (CH[c] << 20) + (RO[c] << 10);   // compile-time constant
        float4 yv = *reinterpret_cast<const float4*>(y + ybase + off);
        float pv = reinterpret_cast<const float*>(&yv)[c & 3];          // wp
        float xv = reinterpret_cast<const float*>(&xr[c >> 2])[c & 3];  // hmod,wp
        acc += fabsf(pv - xv);
    }

    // ---- block reduction: wave-64 shuffle, then 4 wave sums via LDS ----
#pragma unroll
    for (int off = 32; off > 0; off >>= 1)
        acc += __shfl_down(acc, off, 64);

    __shared__ float smem[4];
    unsigned lane = threadIdx.x & 63u;
    unsigned wid  = threadIdx.x >> 6;
    if (lane == 0) smem[wid] = acc;
    __syncthreads();

    if (threadIdx.x == 0)
        partial[blockIdx.x] = (smem[0] + smem[1]) + (smem[2] + smem[3]);
}

__global__ __launch_bounds__(256) void final_reduce_kernel(
        const float* __restrict__ partial, float* __restrict__ out) {
    unsigned t = threadIdx.x;  // 0..255, 2048 partials = 512 float4
    const float4* p4 = reinterpret_cast<const float4*>(partial);
    float4 a = p4[t];
    float4 b = p4[t + 256];
    float acc = (a.x + a.y) + (a.z + a.w) + (b.x + b.y) + (b.z + b.w);

#pragma unroll
    for (int off = 32; off > 0; off >>= 1)
        acc += __shfl_down(acc, off, 64);

    __shared__ float smem[4];
    unsigned lane = t & 63u;
    unsigned wid  = t >> 6;
    if (lane == 0) smem[wid] = acc;
    __syncthreads();

    if (t == 0)
        *out = ((smem[0] + smem[1]) + (smem[2] + smem[3])) * (1.0f / 8388608.0f);
}

extern "C" void kernel_launch(void* const* d_in, const int* in_sizes, int n_in,
                              void* d_out, int out_size, void* d_ws, size_t ws_size,
                              hipStream_t stream) {
    const float* x = (const float*)d_in[0];
    const float* y = (const float*)d_in[1];
    float* out     = (float*)d_out;
    float* partial = (float*)d_ws;   // 2048 floats = 8 KB

    hipLaunchKernelGGL(loss_partial_kernel, dim3(NBLOCKS), dim3(256), 0, stream,
                       x, y, partial);
    hipLaunchKernelGGL(final_reduce_kernel, dim3(1), dim3(256), 0, stream,
                       partial, out);
}